// Round 2
// baseline (2387.479 us; speedup 1.0000x reference)
//
#include <hip/hip_runtime.h>
#include <hip/hip_bf16.h>
#include <math.h>

// Problem dims
#define BSZ 64
#define HGT 32
#define WID 32
#define HWN 1024
#define CCH 684
#define VOC 128
#define NPP 512
#define QCH 256
#define EMB 256
#define HID 256

__device__ __forceinline__ float sigmoid_(float x) {
    return 1.0f / (1.0f + __expf(-x));
}
__device__ __forceinline__ float tanh_(float x) {
    x = fminf(fmaxf(x, -30.0f), 30.0f);
    float e = __expf(2.0f * x);
    return (e - 1.0f) / (e + 1.0f);
}

// ---------------------------------------------------------------------------
// K0: transpose Ua_w (512x684) -> UaT (684x512)
__global__ __launch_bounds__(256) void k_transpose_ua(const float* __restrict__ Ua_w,
                                                      float* __restrict__ UaT) {
    int i = blockIdx.x * 256 + threadIdx.x;
    if (i < CCH * NPP) {
        int c = i >> 9, p = i & 511;
        UaT[i] = Ua_w[p * CCH + c];
    }
}

// ---------------------------------------------------------------------------
// K1: fold conv weights into Uf:  W2T[tap][p] = sum_q Uf_w[p,q]*convQ_w[q,tap]
//     covb[p] = Uf_b[p] + sum_q convQ_b[q]*Uf_w[p,q]
__global__ __launch_bounds__(256) void k_fold_w2(const float* __restrict__ Uf_w,
                                                 const float* __restrict__ Uf_b,
                                                 const float* __restrict__ convQ_w,
                                                 const float* __restrict__ convQ_b,
                                                 float* __restrict__ W2T,
                                                 float* __restrict__ covb) {
    int tap = blockIdx.x;
    int t = threadIdx.x;
    if (tap < 121) {
        for (int p = t; p < NPP; p += 256) {
            float s = 0.f;
            for (int q = 0; q < QCH; q++) s += Uf_w[p * QCH + q] * convQ_w[q * 121 + tap];
            W2T[tap * NPP + p] = s;
        }
    } else {
        for (int p = t; p < NPP; p += 256) {
            float s = Uf_b[p];
            for (int q = 0; q < QCH; q++) s += convQ_b[q] * Uf_w[p * QCH + q];
            covb[p] = s;
        }
    }
}

// ---------------------------------------------------------------------------
// K2: embedding gather + GRU1 + query = pred @ Wa_w.T + Wa_b    (1 block / batch)
__global__ __launch_bounds__(256) void k_embed_gru1(const int* __restrict__ x,
                                                    const float* __restrict__ hidden,
                                                    const float* __restrict__ emb,
                                                    const float* __restrict__ w_ih,
                                                    const float* __restrict__ w_hh,
                                                    const float* __restrict__ b_ih,
                                                    const float* __restrict__ b_hh,
                                                    const float* __restrict__ Wa_w,
                                                    const float* __restrict__ Wa_b,
                                                    float* __restrict__ ws_emb,
                                                    float* __restrict__ ws_pred,
                                                    float* __restrict__ ws_query) {
    int b = blockIdx.x, t = threadIdx.x;
    __shared__ float se[EMB], sh[HID], sp[HID];
    int xi = x[b];
    se[t] = emb[xi * EMB + t];
    sh[t] = hidden[b * HID + t];
    __syncthreads();

    const float* wr = w_ih + (size_t)t * EMB;
    const float* wz = w_ih + (size_t)(t + 256) * EMB;
    const float* wn = w_ih + (size_t)(t + 512) * EMB;
    const float* vr = w_hh + (size_t)t * HID;
    const float* vz = w_hh + (size_t)(t + 256) * HID;
    const float* vn = w_hh + (size_t)(t + 512) * HID;
    float ir = 0, iz = 0, in_ = 0, hr = 0, hz = 0, hn = 0;
    for (int k = 0; k < EMB; k += 4) {
        float4 a0 = *(const float4*)(wr + k);
        float4 a1 = *(const float4*)(wz + k);
        float4 a2 = *(const float4*)(wn + k);
        float4 h0 = *(const float4*)(vr + k);
        float4 h1 = *(const float4*)(vz + k);
        float4 h2 = *(const float4*)(vn + k);
        float e0 = se[k], e1 = se[k + 1], e2 = se[k + 2], e3 = se[k + 3];
        float g0 = sh[k], g1 = sh[k + 1], g2 = sh[k + 2], g3 = sh[k + 3];
        ir += a0.x * e0 + a0.y * e1 + a0.z * e2 + a0.w * e3;
        iz += a1.x * e0 + a1.y * e1 + a1.z * e2 + a1.w * e3;
        in_ += a2.x * e0 + a2.y * e1 + a2.z * e2 + a2.w * e3;
        hr += h0.x * g0 + h0.y * g1 + h0.z * g2 + h0.w * g3;
        hz += h1.x * g0 + h1.y * g1 + h1.z * g2 + h1.w * g3;
        hn += h2.x * g0 + h2.y * g1 + h2.z * g2 + h2.w * g3;
    }
    float r = sigmoid_(ir + b_ih[t] + hr + b_hh[t]);
    float z = sigmoid_(iz + b_ih[256 + t] + hz + b_hh[256 + t]);
    float n = tanh_(in_ + b_ih[512 + t] + r * (hn + b_hh[512 + t]));
    float pred = (1.0f - z) * n + z * sh[t];
    ws_emb[b * EMB + t] = se[t];
    ws_pred[b * HID + t] = pred;
    sp[t] = pred;
    __syncthreads();

    // query: rows t and t+256 of Wa_w (512x256)
    for (int jj = 0; jj < 2; jj++) {
        int j = t + jj * 256;
        const float* wq = Wa_w + (size_t)j * HID;
        float q = Wa_b[j];
        for (int k = 0; k < HID; k += 4) {
            float4 a = *(const float4*)(wq + k);
            q += a.x * sp[k] + a.y * sp[k + 1] + a.z * sp[k + 2] + a.w * sp[k + 3];
        }
        ws_query[b * NPP + j] = q;
    }
}

// ---------------------------------------------------------------------------
// K3: fused score kernel. One block = (batch b, image row r) = 32 hw positions.
// acc[32 hw][512 p] = query + covb + Ua_b + feature.Ua + cover-stencil,
// then e_t = Va . tanh(acc) + Va_b.
__global__ __launch_bounds__(256) void k_score(const float* __restrict__ feature,
                                               const float* __restrict__ alpha,
                                               const float* __restrict__ UaT,
                                               const float* __restrict__ W2T,
                                               const float* __restrict__ covb,
                                               const float* __restrict__ Ua_b,
                                               const float* __restrict__ Va_w,
                                               const float* __restrict__ Va_b,
                                               const float* __restrict__ ws_query,
                                               float* __restrict__ ws_et) {
    int r = blockIdx.x;   // image row 0..31
    int b = blockIdx.y;   // batch
    int tid = threadIdx.x;
    int ti = tid >> 5, tj = tid & 31;  // ti: 8 col-groups, tj: 32 p-lanes

    __shared__ __align__(16) float s_b[16][512];   // B tile (UaT / W2T chunk)
    __shared__ float s_a[16][32];                  // A tile (feature chunk)
    __shared__ float s_halo[11][42];               // beta halo for stencil
    __shared__ float s_va[512];

    s_va[tid] = Va_w[tid];
    s_va[tid + 256] = Va_w[tid + 256];
    for (int idx = tid; idx < 11 * 42; idx += 256) {
        int hr_ = idx / 42, hc = idx - hr_ * 42;
        int y = r - 5 + hr_, xx = hc - 5;
        float v = 0.f;
        if (y >= 0 && y < HGT && xx >= 0 && xx < WID) v = alpha[b * HWN + y * WID + xx];
        s_halo[hr_][hc] = v;
    }

    float acc[4][16];
#pragma unroll
    for (int ni = 0; ni < 16; ni++) {
        int p = tj + 32 * ni;
        float q0 = ws_query[b * NPP + p] + covb[p] + Ua_b[p];
#pragma unroll
        for (int mi = 0; mi < 4; mi++) acc[mi][ni] = q0;
    }

    const float* fbase = feature + ((size_t)b * CCH) * HWN + r * WID;

    // ---- key_t: K-loop over channels ----
    for (int c0 = 0; c0 < CCH; c0 += 16) {
        __syncthreads();
#pragma unroll
        for (int l = 0; l < 2; l++) {
            int idx = tid + l * 256;
            int cl = idx >> 5, col = idx & 31;
            int c = c0 + cl;
            s_a[cl][col] = (c < CCH) ? fbase[(size_t)c * HWN + col] : 0.f;
        }
#pragma unroll
        for (int l = 0; l < 8; l++) {
            int idx4 = tid + l * 256;
            int cl = idx4 >> 7, p4 = idx4 & 127;
            int c = c0 + cl;
            float4 v = make_float4(0.f, 0.f, 0.f, 0.f);
            if (c < CCH) v = *(const float4*)(UaT + (size_t)c * NPP + p4 * 4);
            *(float4*)(&s_b[cl][p4 * 4]) = v;
        }
        __syncthreads();
#pragma unroll
        for (int kk = 0; kk < 16; kk++) {
            float a0 = s_a[kk][ti * 4 + 0];
            float a1 = s_a[kk][ti * 4 + 1];
            float a2 = s_a[kk][ti * 4 + 2];
            float a3 = s_a[kk][ti * 4 + 3];
#pragma unroll
            for (int ni = 0; ni < 16; ni++) {
                float bv = s_b[kk][tj + 32 * ni];
                acc[0][ni] += a0 * bv;
                acc[1][ni] += a1 * bv;
                acc[2][ni] += a2 * bv;
                acc[3][ni] += a3 * bv;
            }
        }
    }

    // ---- cover: 121-tap stencil with folded weights ----
    for (int t0 = 0; t0 < 121; t0 += 16) {
        __syncthreads();
#pragma unroll
        for (int l = 0; l < 8; l++) {
            int idx4 = tid + l * 256;
            int cl = idx4 >> 7, p4 = idx4 & 127;
            int tap = t0 + cl;
            float4 v = make_float4(0.f, 0.f, 0.f, 0.f);
            if (tap < 121) v = *(const float4*)(W2T + (size_t)tap * NPP + p4 * 4);
            *(float4*)(&s_b[cl][p4 * 4]) = v;
        }
        __syncthreads();
        int ntap = min(16, 121 - t0);
        for (int kk = 0; kk < ntap; kk++) {
            int tap = t0 + kk;
            int ky = tap / 11, kx = tap - ky * 11;
            float a0 = s_halo[ky][ti * 4 + 0 + kx];
            float a1 = s_halo[ky][ti * 4 + 1 + kx];
            float a2 = s_halo[ky][ti * 4 + 2 + kx];
            float a3 = s_halo[ky][ti * 4 + 3 + kx];
#pragma unroll
            for (int ni = 0; ni < 16; ni++) {
                float bv = s_b[kk][tj + 32 * ni];
                acc[0][ni] += a0 * bv;
                acc[1][ni] += a1 * bv;
                acc[2][ni] += a2 * bv;
                acc[3][ni] += a3 * bv;
            }
        }
    }

    // ---- tanh + Va reduce -> e_t ----
    float part[4] = {0.f, 0.f, 0.f, 0.f};
#pragma unroll
    for (int ni = 0; ni < 16; ni++) {
        int p = tj + 32 * ni;
        float va = s_va[p];
#pragma unroll
        for (int mi = 0; mi < 4; mi++) part[mi] += va * tanh_(acc[mi][ni]);
    }
#pragma unroll
    for (int off = 16; off >= 1; off >>= 1) {
#pragma unroll
        for (int mi = 0; mi < 4; mi++) part[mi] += __shfl_xor(part[mi], off, 64);
    }
    if (tj == 0) {
        float vb = Va_b[0];
#pragma unroll
        for (int mi = 0; mi < 4; mi++)
            ws_et[b * HWN + r * WID + ti * 4 + mi] = part[mi] + vb;
    }
}

// ---------------------------------------------------------------------------
// K4: softmax over 1024 positions per batch (exact ref semantics: exp, no shift)
__global__ __launch_bounds__(256) void k_softmax(const float* __restrict__ ws_et,
                                                 float* __restrict__ alpha_out) {
    int b = blockIdx.x, t = threadIdx.x;
    __shared__ float red[4];
    float e[4];
    float s = 0.f;
#pragma unroll
    for (int i = 0; i < 4; i++) {
        e[i] = expf(ws_et[b * HWN + t + i * 256]);
        s += e[i];
    }
#pragma unroll
    for (int off = 32; off >= 1; off >>= 1) s += __shfl_xor(s, off, 64);
    int wid = t >> 6;
    if ((t & 63) == 0) red[wid] = s;
    __syncthreads();
    float tot = red[0] + red[1] + red[2] + red[3] + 1e-8f;
    float inv = 1.0f / tot;
#pragma unroll
    for (int i = 0; i < 4; i++) alpha_out[b * HWN + t + i * 256] = e[i] * inv;
}

// ---------------------------------------------------------------------------
// K5: context[b,c] = sum_hw feature[b,c,hw] * alpha[b,hw]   (1 wave per (b,c))
__global__ __launch_bounds__(256) void k_context(const float* __restrict__ feature,
                                                 const float* __restrict__ alpha_out,
                                                 float* __restrict__ ws_ctx) {
    int b = blockIdx.x;
    int c = blockIdx.y * 4 + (threadIdx.x >> 6);
    int lane = threadIdx.x & 63;
    const float* f = feature + ((size_t)b * CCH + c) * HWN;
    const float* a = alpha_out + b * HWN;
    float s = 0.f;
    for (int k = lane; k < HWN; k += 64) s += f[k] * a[k];
#pragma unroll
    for (int off = 32; off >= 1; off >>= 1) s += __shfl_xor(s, off, 64);
    if (lane == 0) ws_ctx[b * CCH + c] = s;
}

// ---------------------------------------------------------------------------
// K6: GRU2 + output head + pair-max + logits   (1 block / batch)
__global__ __launch_bounds__(256) void k_final(const float* __restrict__ ws_ctx,
                                               const float* __restrict__ ws_pred,
                                               const float* __restrict__ ws_emb,
                                               const float* __restrict__ w_ih2,
                                               const float* __restrict__ w_hh2,
                                               const float* __restrict__ b_ih2,
                                               const float* __restrict__ b_hh2,
                                               const float* __restrict__ Ws_w,
                                               const float* __restrict__ Ws_b,
                                               const float* __restrict__ Wc_w,
                                               const float* __restrict__ Wc_b,
                                               const float* __restrict__ Wo_w,
                                               const float* __restrict__ Wo_b,
                                               float* __restrict__ out_logits,
                                               float* __restrict__ out_h2) {
    int b = blockIdx.x, t = threadIdx.x;
    __shared__ float sc[CCH], sp[HID], semb[EMB], sh2[HID], so[EMB], som[VOC];
    for (int i = t; i < CCH; i += 256) sc[i] = ws_ctx[b * CCH + i];
    sp[t] = ws_pred[b * HID + t];
    semb[t] = ws_emb[b * EMB + t];
    __syncthreads();

    const float* wr = w_ih2 + (size_t)t * CCH;
    const float* wz = w_ih2 + (size_t)(t + 256) * CCH;
    const float* wn = w_ih2 + (size_t)(t + 512) * CCH;
    float ir = 0, iz = 0, in_ = 0;
    for (int k = 0; k < CCH; k += 4) {
        float4 a0 = *(const float4*)(wr + k);
        float4 a1 = *(const float4*)(wz + k);
        float4 a2 = *(const float4*)(wn + k);
        float c0 = sc[k], c1 = sc[k + 1], c2 = sc[k + 2], c3 = sc[k + 3];
        ir += a0.x * c0 + a0.y * c1 + a0.z * c2 + a0.w * c3;
        iz += a1.x * c0 + a1.y * c1 + a1.z * c2 + a1.w * c3;
        in_ += a2.x * c0 + a2.y * c1 + a2.z * c2 + a2.w * c3;
    }
    const float* vr = w_hh2 + (size_t)t * HID;
    const float* vz = w_hh2 + (size_t)(t + 256) * HID;
    const float* vn = w_hh2 + (size_t)(t + 512) * HID;
    float hr = 0, hz = 0, hn = 0;
    for (int k = 0; k < HID; k += 4) {
        float4 h0 = *(const float4*)(vr + k);
        float4 h1 = *(const float4*)(vz + k);
        float4 h2v = *(const float4*)(vn + k);
        float g0 = sp[k], g1 = sp[k + 1], g2 = sp[k + 2], g3 = sp[k + 3];
        hr += h0.x * g0 + h0.y * g1 + h0.z * g2 + h0.w * g3;
        hz += h1.x * g0 + h1.y * g1 + h1.z * g2 + h1.w * g3;
        hn += h2v.x * g0 + h2v.y * g1 + h2v.z * g2 + h2v.w * g3;
    }
    float rg = sigmoid_(ir + b_ih2[t] + hr + b_hh2[t]);
    float zg = sigmoid_(iz + b_ih2[256 + t] + hz + b_hh2[256 + t]);
    float ng = tanh_(in_ + b_ih2[512 + t] + rg * (hn + b_hh2[512 + t]));
    float h2 = (1.0f - zg) * ng + zg * sp[t];
    out_h2[b * HID + t] = h2;
    sh2[t] = h2;
    __syncthreads();

    // o = embedded + h2 @ Ws.T + Ws_b + context @ Wc.T + Wc_b
    const float* ws_row = Ws_w + (size_t)t * HID;
    const float* wc_row = Wc_w + (size_t)t * CCH;
    float o = semb[t] + Ws_b[t] + Wc_b[t];
    for (int k = 0; k < HID; k += 4) {
        float4 a = *(const float4*)(ws_row + k);
        o += a.x * sh2[k] + a.y * sh2[k + 1] + a.z * sh2[k + 2] + a.w * sh2[k + 3];
    }
    for (int k = 0; k < CCH; k += 4) {
        float4 a = *(const float4*)(wc_row + k);
        o += a.x * sc[k] + a.y * sc[k + 1] + a.z * sc[k + 2] + a.w * sc[k + 3];
    }
    so[t] = o;
    __syncthreads();
    if (t < VOC) som[t] = fmaxf(so[2 * t], so[2 * t + 1]);
    __syncthreads();
    if (t < VOC) {
        const float* wo_row = Wo_w + (size_t)t * VOC;
        float lg = Wo_b[t];
        for (int k = 0; k < VOC; k += 4) {
            float4 a = *(const float4*)(wo_row + k);
            lg += a.x * som[k] + a.y * som[k + 1] + a.z * som[k + 2] + a.w * som[k + 3];
        }
        out_logits[b * VOC + t] = lg;
    }
}

// ---------------------------------------------------------------------------
extern "C" void kernel_launch(void* const* d_in, const int* in_sizes, int n_in,
                              void* d_out, int out_size, void* d_ws, size_t ws_size,
                              hipStream_t stream) {
    const int* x = (const int*)d_in[0];
    const float* hidden = (const float*)d_in[1];
    const float* feature = (const float*)d_in[2];
    const float* alpha = (const float*)d_in[3];
    const float* emb = (const float*)d_in[4];
    const float* gru1_wih = (const float*)d_in[5];
    const float* gru1_whh = (const float*)d_in[6];
    const float* gru1_bih = (const float*)d_in[7];
    const float* gru1_bhh = (const float*)d_in[8];
    const float* gru2_wih = (const float*)d_in[9];
    const float* gru2_whh = (const float*)d_in[10];
    const float* gru2_bih = (const float*)d_in[11];
    const float* gru2_bhh = (const float*)d_in[12];
    const float* convQ_w = (const float*)d_in[13];
    const float* convQ_b = (const float*)d_in[14];
    const float* Wa_w = (const float*)d_in[15];
    const float* Wa_b = (const float*)d_in[16];
    const float* Ua_w = (const float*)d_in[17];
    const float* Ua_b = (const float*)d_in[18];
    const float* Uf_w = (const float*)d_in[19];
    const float* Uf_b = (const float*)d_in[20];
    const float* Va_w = (const float*)d_in[21];
    const float* Va_b = (const float*)d_in[22];
    const float* Ws_w = (const float*)d_in[23];
    const float* Ws_b = (const float*)d_in[24];
    const float* Wc_w = (const float*)d_in[25];
    const float* Wc_b = (const float*)d_in[26];
    const float* Wo_w = (const float*)d_in[27];
    const float* Wo_b = (const float*)d_in[28];

    float* out = (float*)d_out;
    float* out_logits = out;                 // 64*128
    float* out_h2 = out + BSZ * VOC;         // 64*256
    float* out_alpha = out + BSZ * VOC + BSZ * HID;  // 64*1024

    float* ws = (float*)d_ws;
    float* ws_emb = ws;                      // 16384
    float* ws_pred = ws + 16384;             // 16384
    float* ws_query = ws + 32768;            // 32768
    float* ws_et = ws + 65536;               // 65536
    float* ws_ctx = ws + 131072;             // 43776 (-> 175104 aligned)
    float* ws_W2T = ws + 175104;             // 61952
    float* ws_covb = ws + 237056;            // 512
    float* ws_UaT = ws + 237568;             // 350208; end 587776 floats (2.35 MB)

    k_transpose_ua<<<(CCH * NPP + 255) / 256, 256, 0, stream>>>(Ua_w, ws_UaT);
    k_fold_w2<<<122, 256, 0, stream>>>(Uf_w, Uf_b, convQ_w, convQ_b, ws_W2T, ws_covb);
    k_embed_gru1<<<BSZ, 256, 0, stream>>>(x, hidden, emb, gru1_wih, gru1_whh,
                                          gru1_bih, gru1_bhh, Wa_w, Wa_b,
                                          ws_emb, ws_pred, ws_query);
    k_score<<<dim3(32, BSZ), 256, 0, stream>>>(feature, alpha, ws_UaT, ws_W2T,
                                               ws_covb, Ua_b, Va_w, Va_b,
                                               ws_query, ws_et);
    k_softmax<<<BSZ, 256, 0, stream>>>(ws_et, out_alpha);
    k_context<<<dim3(BSZ, 171), 256, 0, stream>>>(feature, out_alpha, ws_ctx);
    k_final<<<BSZ, 256, 0, stream>>>(ws_ctx, ws_pred, ws_emb, gru2_wih, gru2_whh,
                                     gru2_bih, gru2_bhh, Ws_w, Ws_b, Wc_w, Wc_b,
                                     Wo_w, Wo_b, out_logits, out_h2);
}

// Round 3
// 693.179 us; speedup vs baseline: 3.4442x; 3.4442x over previous
//
#include <hip/hip_runtime.h>
#include <hip/hip_bf16.h>
#include <math.h>

// Problem dims
#define BSZ 64
#define HGT 32
#define WID 32
#define HWN 1024
#define CCH 684
#define KP 704      // CCH padded to 22*32
#define VOC 128
#define NPP 512
#define QCH 256
#define EMB 256
#define HID 256
#define TAPP 128    // 121 taps padded

typedef __attribute__((ext_vector_type(8))) short short8v;
typedef __attribute__((ext_vector_type(4))) float f32x4;

__device__ __forceinline__ float sigmoid_(float x) {
    return 1.0f / (1.0f + __expf(-x));
}
__device__ __forceinline__ float tanh_(float x) {
    x = fminf(fmaxf(x, -30.0f), 30.0f);
    float e = __expf(2.0f * x);
    return (e - 1.0f) / (e + 1.0f);
}
__device__ __forceinline__ unsigned short f2bf(float f) {
    unsigned int u = __float_as_uint(f);
    u = (u + 0x7FFFu + ((u >> 16) & 1u)) >> 16;
    return (unsigned short)u;
}

// ---------------------------------------------------------------------------
// K0: convert Ua_w (512x684 fp32, [p][c] k-contiguous) -> Ua_bf [512][704] bf16
__global__ __launch_bounds__(256) void k_prep_ua(const float* __restrict__ Ua_w,
                                                 unsigned short* __restrict__ Ua_bf) {
    int p = blockIdx.x;
    for (int c = threadIdx.x; c < KP; c += 256) {
        unsigned short v = 0;
        if (c < CCH) v = f2bf(Ua_w[p * CCH + c]);
        Ua_bf[p * KP + c] = v;
    }
}

// ---------------------------------------------------------------------------
// K1: fold conv weights into Uf: W2_bf[p][tap] = sum_q Uf_w[p,q]*convQ_w[q,tap]
//     covb[p] = Uf_b[p] + sum_q convQ_b[q]*Uf_w[p,q]
__global__ __launch_bounds__(256) void k_fold_w2(const float* __restrict__ Uf_w,
                                                 const float* __restrict__ Uf_b,
                                                 const float* __restrict__ convQ_w,
                                                 const float* __restrict__ convQ_b,
                                                 unsigned short* __restrict__ W2_bf,
                                                 float* __restrict__ covb) {
    int tap = blockIdx.x;
    int t = threadIdx.x;
    if (tap < TAPP) {
        for (int p = t; p < NPP; p += 256) {
            unsigned short v = 0;
            if (tap < 121) {
                float s = 0.f;
                for (int q = 0; q < QCH; q++) s += Uf_w[p * QCH + q] * convQ_w[q * 121 + tap];
                v = f2bf(s);
            }
            W2_bf[p * TAPP + tap] = v;
        }
    } else {
        for (int p = t; p < NPP; p += 256) {
            float s = Uf_b[p];
            for (int q = 0; q < QCH; q++) s += convQ_b[q] * Uf_w[p * QCH + q];
            covb[p] = s;
        }
    }
}

// ---------------------------------------------------------------------------
// K2: embedding gather + GRU1 + q0 = pred @ Wa_w.T + Wa_b + covb + Ua_b
__global__ __launch_bounds__(256) void k_embed_gru1(const int* __restrict__ x,
                                                    const float* __restrict__ hidden,
                                                    const float* __restrict__ emb,
                                                    const float* __restrict__ w_ih,
                                                    const float* __restrict__ w_hh,
                                                    const float* __restrict__ b_ih,
                                                    const float* __restrict__ b_hh,
                                                    const float* __restrict__ Wa_w,
                                                    const float* __restrict__ Wa_b,
                                                    const float* __restrict__ covb,
                                                    const float* __restrict__ Ua_b,
                                                    float* __restrict__ ws_emb,
                                                    float* __restrict__ ws_pred,
                                                    float* __restrict__ ws_q0) {
    int b = blockIdx.x, t = threadIdx.x;
    __shared__ float se[EMB], sh[HID], sp[HID];
    int xi = x[b];
    se[t] = emb[xi * EMB + t];
    sh[t] = hidden[b * HID + t];
    __syncthreads();

    const float* wr = w_ih + (size_t)t * EMB;
    const float* wz = w_ih + (size_t)(t + 256) * EMB;
    const float* wn = w_ih + (size_t)(t + 512) * EMB;
    const float* vr = w_hh + (size_t)t * HID;
    const float* vz = w_hh + (size_t)(t + 256) * HID;
    const float* vn = w_hh + (size_t)(t + 512) * HID;
    float ir = 0, iz = 0, in_ = 0, hr = 0, hz = 0, hn = 0;
    for (int k = 0; k < EMB; k += 4) {
        float4 a0 = *(const float4*)(wr + k);
        float4 a1 = *(const float4*)(wz + k);
        float4 a2 = *(const float4*)(wn + k);
        float4 h0 = *(const float4*)(vr + k);
        float4 h1 = *(const float4*)(vz + k);
        float4 h2 = *(const float4*)(vn + k);
        float e0 = se[k], e1 = se[k + 1], e2 = se[k + 2], e3 = se[k + 3];
        float g0 = sh[k], g1 = sh[k + 1], g2 = sh[k + 2], g3 = sh[k + 3];
        ir += a0.x * e0 + a0.y * e1 + a0.z * e2 + a0.w * e3;
        iz += a1.x * e0 + a1.y * e1 + a1.z * e2 + a1.w * e3;
        in_ += a2.x * e0 + a2.y * e1 + a2.z * e2 + a2.w * e3;
        hr += h0.x * g0 + h0.y * g1 + h0.z * g2 + h0.w * g3;
        hz += h1.x * g0 + h1.y * g1 + h1.z * g2 + h1.w * g3;
        hn += h2.x * g0 + h2.y * g1 + h2.z * g2 + h2.w * g3;
    }
    float r = sigmoid_(ir + b_ih[t] + hr + b_hh[t]);
    float z = sigmoid_(iz + b_ih[256 + t] + hz + b_hh[256 + t]);
    float n = tanh_(in_ + b_ih[512 + t] + r * (hn + b_hh[512 + t]));
    float pred = (1.0f - z) * n + z * sh[t];
    ws_emb[b * EMB + t] = se[t];
    ws_pred[b * HID + t] = pred;
    sp[t] = pred;
    __syncthreads();

    for (int jj = 0; jj < 2; jj++) {
        int j = t + jj * 256;
        const float* wq = Wa_w + (size_t)j * HID;
        float q = Wa_b[j] + covb[j] + Ua_b[j];
        for (int k = 0; k < HID; k += 4) {
            float4 a = *(const float4*)(wq + k);
            q += a.x * sp[k] + a.y * sp[k + 1] + a.z * sp[k + 2] + a.w * sp[k + 3];
        }
        ws_q0[b * NPP + j] = q;
    }
}

// ---------------------------------------------------------------------------
// K3: MFMA fused score kernel. Block = (rb 0..15, b): 64 hw rows x 512 p.
// 4 waves, each 64x128 via 16x16x32 bf16 MFMA. key_t GEMM (K=704) + folded
// cover stencil (K=128) + q0 + tanh + Va reduce -> e_t.
__global__ __launch_bounds__(256, 2) void k_score(const float* __restrict__ feature,
                                                  const float* __restrict__ alpha,
                                                  const unsigned short* __restrict__ Ua_bf,
                                                  const unsigned short* __restrict__ W2_bf,
                                                  const float* __restrict__ ws_q0,
                                                  const float* __restrict__ Va_w,
                                                  const float* __restrict__ Va_b,
                                                  float* __restrict__ ws_et) {
    int rb = blockIdx.x;   // row-block: hw in [rb*64, rb*64+64)
    int b = blockIdx.y;
    int tid = threadIdx.x;
    int wv = tid >> 6;
    int lane = tid & 63;
    int li = lane & 15;            // col within 16 / row within A frag
    int k08 = (lane >> 4) * 8;     // k-run start within 32-K step
    int pbase = wv * 128;

    __shared__ unsigned short s_a[64 * 40];    // A tile [64 hw][32 k], stride 40
    __shared__ unsigned short s_a2[64 * 136];  // stencil A [64 hw][128 tap], stride 136
    __shared__ float s_et[64];

    // ---- build stencil operand A2 (beta halo, bf16) ----
    for (int idx = tid; idx < 64 * 128; idx += 256) {
        int hwl = idx >> 7, tap = idx & 127;
        unsigned short v = 0;
        if (tap < 121) {
            int ky = tap / 11, kx = tap - ky * 11;
            int hwg = rb * 64 + hwl;
            int y = (hwg >> 5) + ky - 5;
            int xx = (hwg & 31) + kx - 5;
            if (y >= 0 && y < HGT && xx >= 0 && xx < WID)
                v = f2bf(alpha[b * HWN + y * WID + xx]);
        }
        s_a2[hwl * 136 + tap] = v;
    }
    if (tid < 64) s_et[tid] = 0.f;

    f32x4 acc[4][8];
#pragma unroll
    for (int mt = 0; mt < 4; mt++)
#pragma unroll
        for (int nt = 0; nt < 8; nt++) acc[mt][nt] = (f32x4){0.f, 0.f, 0.f, 0.f};

    const float* fbase = feature + (size_t)b * CCH * HWN + rb * 64;
    int p2 = tid & 15, g = tid >> 4;
    unsigned int* s_a_u32 = (unsigned int*)s_a;

    // ---- key_t: 22 K-steps of 32 channels ----
    for (int s = 0; s < 22; s++) {
        int c0 = s * 32;
        __syncthreads();
        {   // stage A: feature fp32 [32 c][64 hw] -> bf16 LDS [64 hw][32 k]
            int c1 = c0 + 2 * p2;
            float4 f0 = make_float4(0.f, 0.f, 0.f, 0.f), f1 = f0;
            if (c1 < CCH) {
                f0 = *(const float4*)(fbase + (size_t)c1 * HWN + g * 4);
                f1 = *(const float4*)(fbase + (size_t)(c1 + 1) * HWN + g * 4);
            }
            s_a_u32[(g * 4 + 0) * 20 + p2] = (unsigned int)f2bf(f0.x) | ((unsigned int)f2bf(f1.x) << 16);
            s_a_u32[(g * 4 + 1) * 20 + p2] = (unsigned int)f2bf(f0.y) | ((unsigned int)f2bf(f1.y) << 16);
            s_a_u32[(g * 4 + 2) * 20 + p2] = (unsigned int)f2bf(f0.z) | ((unsigned int)f2bf(f1.z) << 16);
            s_a_u32[(g * 4 + 3) * 20 + p2] = (unsigned int)f2bf(f0.w) | ((unsigned int)f2bf(f1.w) << 16);
        }
        __syncthreads();
        short8v af[4];
#pragma unroll
        for (int mt = 0; mt < 4; mt++)
            af[mt] = *reinterpret_cast<const short8v*>(&s_a[(mt * 16 + li) * 40 + k08]);
#pragma unroll
        for (int nt = 0; nt < 8; nt++) {
            short8v bv = *reinterpret_cast<const short8v*>(
                Ua_bf + (size_t)(pbase + nt * 16 + li) * KP + c0 + k08);
#pragma unroll
            for (int mt = 0; mt < 4; mt++)
                acc[mt][nt] = __builtin_amdgcn_mfma_f32_16x16x32_bf16(af[mt], bv, acc[mt][nt], 0, 0, 0);
        }
    }

    // ---- cover stencil: 4 K-steps of 32 taps ----
#pragma unroll
    for (int s = 0; s < 4; s++) {
        int t0 = s * 32;
        short8v af[4];
#pragma unroll
        for (int mt = 0; mt < 4; mt++)
            af[mt] = *reinterpret_cast<const short8v*>(&s_a2[(mt * 16 + li) * 136 + t0 + k08]);
#pragma unroll
        for (int nt = 0; nt < 8; nt++) {
            short8v bv = *reinterpret_cast<const short8v*>(
                W2_bf + (size_t)(pbase + nt * 16 + li) * TAPP + t0 + k08);
#pragma unroll
            for (int mt = 0; mt < 4; mt++)
                acc[mt][nt] = __builtin_amdgcn_mfma_f32_16x16x32_bf16(af[mt], bv, acc[mt][nt], 0, 0, 0);
        }
    }

    // ---- epilogue: +q0, tanh, *Va, reduce over p ----
    float part[4][4];
#pragma unroll
    for (int mt = 0; mt < 4; mt++)
#pragma unroll
        for (int r = 0; r < 4; r++) part[mt][r] = 0.f;

#pragma unroll
    for (int nt = 0; nt < 8; nt++) {
        int p = pbase + nt * 16 + li;
        float q0 = ws_q0[b * NPP + p];
        float va = Va_w[p];
#pragma unroll
        for (int mt = 0; mt < 4; mt++)
#pragma unroll
            for (int r = 0; r < 4; r++)
                part[mt][r] += va * tanh_(acc[mt][nt][r] + q0);
    }
#pragma unroll
    for (int mask = 1; mask <= 8; mask <<= 1)
#pragma unroll
        for (int mt = 0; mt < 4; mt++)
#pragma unroll
            for (int r = 0; r < 4; r++)
                part[mt][r] += __shfl_xor(part[mt][r], mask, 64);

    if (li == 0) {
        int rb4 = (lane >> 4) * 4;
#pragma unroll
        for (int mt = 0; mt < 4; mt++)
#pragma unroll
            for (int r = 0; r < 4; r++)
                atomicAdd(&s_et[mt * 16 + rb4 + r], part[mt][r]);
    }
    __syncthreads();
    if (tid < 64) ws_et[b * HWN + rb * 64 + tid] = s_et[tid] + Va_b[0];
}

// ---------------------------------------------------------------------------
// K4: softmax over 1024 positions per batch (exact ref semantics: exp, no shift)
__global__ __launch_bounds__(256) void k_softmax(const float* __restrict__ ws_et,
                                                 float* __restrict__ alpha_out) {
    int b = blockIdx.x, t = threadIdx.x;
    __shared__ float red[4];
    float e[4];
    float s = 0.f;
#pragma unroll
    for (int i = 0; i < 4; i++) {
        e[i] = expf(ws_et[b * HWN + t + i * 256]);
        s += e[i];
    }
#pragma unroll
    for (int off = 32; off >= 1; off >>= 1) s += __shfl_xor(s, off, 64);
    int wid = t >> 6;
    if ((t & 63) == 0) red[wid] = s;
    __syncthreads();
    float tot = red[0] + red[1] + red[2] + red[3] + 1e-8f;
    float inv = 1.0f / tot;
#pragma unroll
    for (int i = 0; i < 4; i++) alpha_out[b * HWN + t + i * 256] = e[i] * inv;
}

// ---------------------------------------------------------------------------
// K5: context[b,c] = sum_hw feature[b,c,hw] * alpha[b,hw]   (1 wave per (b,c))
__global__ __launch_bounds__(256) void k_context(const float* __restrict__ feature,
                                                 const float* __restrict__ alpha_out,
                                                 float* __restrict__ ws_ctx) {
    int b = blockIdx.x;
    int c = blockIdx.y * 4 + (threadIdx.x >> 6);
    int lane = threadIdx.x & 63;
    const float* f = feature + ((size_t)b * CCH + c) * HWN;
    const float* a = alpha_out + b * HWN;
    float s = 0.f;
    for (int k = lane; k < HWN; k += 64) s += f[k] * a[k];
#pragma unroll
    for (int off = 32; off >= 1; off >>= 1) s += __shfl_xor(s, off, 64);
    if (lane == 0) ws_ctx[b * CCH + c] = s;
}

// ---------------------------------------------------------------------------
// K6: GRU2 + output head + pair-max + logits   (1 block / batch)
__global__ __launch_bounds__(256) void k_final(const float* __restrict__ ws_ctx,
                                               const float* __restrict__ ws_pred,
                                               const float* __restrict__ ws_emb,
                                               const float* __restrict__ w_ih2,
                                               const float* __restrict__ w_hh2,
                                               const float* __restrict__ b_ih2,
                                               const float* __restrict__ b_hh2,
                                               const float* __restrict__ Ws_w,
                                               const float* __restrict__ Ws_b,
                                               const float* __restrict__ Wc_w,
                                               const float* __restrict__ Wc_b,
                                               const float* __restrict__ Wo_w,
                                               const float* __restrict__ Wo_b,
                                               float* __restrict__ out_logits,
                                               float* __restrict__ out_h2) {
    int b = blockIdx.x, t = threadIdx.x;
    __shared__ float sc[CCH], sp[HID], semb[EMB], sh2[HID], so[EMB], som[VOC];
    for (int i = t; i < CCH; i += 256) sc[i] = ws_ctx[b * CCH + i];
    sp[t] = ws_pred[b * HID + t];
    semb[t] = ws_emb[b * EMB + t];
    __syncthreads();

    const float* wr = w_ih2 + (size_t)t * CCH;
    const float* wz = w_ih2 + (size_t)(t + 256) * CCH;
    const float* wn = w_ih2 + (size_t)(t + 512) * CCH;
    float ir = 0, iz = 0, in_ = 0;
    for (int k = 0; k < CCH; k += 4) {
        float4 a0 = *(const float4*)(wr + k);
        float4 a1 = *(const float4*)(wz + k);
        float4 a2 = *(const float4*)(wn + k);
        float c0 = sc[k], c1 = sc[k + 1], c2 = sc[k + 2], c3 = sc[k + 3];
        ir += a0.x * c0 + a0.y * c1 + a0.z * c2 + a0.w * c3;
        iz += a1.x * c0 + a1.y * c1 + a1.z * c2 + a1.w * c3;
        in_ += a2.x * c0 + a2.y * c1 + a2.z * c2 + a2.w * c3;
    }
    const float* vr = w_hh2 + (size_t)t * HID;
    const float* vz = w_hh2 + (size_t)(t + 256) * HID;
    const float* vn = w_hh2 + (size_t)(t + 512) * HID;
    float hr = 0, hz = 0, hn = 0;
    for (int k = 0; k < HID; k += 4) {
        float4 h0 = *(const float4*)(vr + k);
        float4 h1 = *(const float4*)(vz + k);
        float4 h2v = *(const float4*)(vn + k);
        float g0 = sp[k], g1 = sp[k + 1], g2 = sp[k + 2], g3 = sp[k + 3];
        hr += h0.x * g0 + h0.y * g1 + h0.z * g2 + h0.w * g3;
        hz += h1.x * g0 + h1.y * g1 + h1.z * g2 + h1.w * g3;
        hn += h2v.x * g0 + h2v.y * g1 + h2v.z * g2 + h2v.w * g3;
    }
    float rg = sigmoid_(ir + b_ih2[t] + hr + b_hh2[t]);
    float zg = sigmoid_(iz + b_ih2[256 + t] + hz + b_hh2[256 + t]);
    float ng = tanh_(in_ + b_ih2[512 + t] + rg * (hn + b_hh2[512 + t]));
    float h2 = (1.0f - zg) * ng + zg * sp[t];
    out_h2[b * HID + t] = h2;
    sh2[t] = h2;
    __syncthreads();

    const float* ws_row = Ws_w + (size_t)t * HID;
    const float* wc_row = Wc_w + (size_t)t * CCH;
    float o = semb[t] + Ws_b[t] + Wc_b[t];
    for (int k = 0; k < HID; k += 4) {
        float4 a = *(const float4*)(ws_row + k);
        o += a.x * sh2[k] + a.y * sh2[k + 1] + a.z * sh2[k + 2] + a.w * sh2[k + 3];
    }
    for (int k = 0; k < CCH; k += 4) {
        float4 a = *(const float4*)(wc_row + k);
        o += a.x * sc[k] + a.y * sc[k + 1] + a.z * sc[k + 2] + a.w * sc[k + 3];
    }
    so[t] = o;
    __syncthreads();
    if (t < VOC) som[t] = fmaxf(so[2 * t], so[2 * t + 1]);
    __syncthreads();
    if (t < VOC) {
        const float* wo_row = Wo_w + (size_t)t * VOC;
        float lg = Wo_b[t];
        for (int k = 0; k < VOC; k += 4) {
            float4 a = *(const float4*)(wo_row + k);
            lg += a.x * som[k] + a.y * som[k + 1] + a.z * som[k + 2] + a.w * som[k + 3];
        }
        out_logits[b * VOC + t] = lg;
    }
}

// ---------------------------------------------------------------------------
extern "C" void kernel_launch(void* const* d_in, const int* in_sizes, int n_in,
                              void* d_out, int out_size, void* d_ws, size_t ws_size,
                              hipStream_t stream) {
    const int* x = (const int*)d_in[0];
    const float* hidden = (const float*)d_in[1];
    const float* feature = (const float*)d_in[2];
    const float* alpha = (const float*)d_in[3];
    const float* emb = (const float*)d_in[4];
    const float* gru1_wih = (const float*)d_in[5];
    const float* gru1_whh = (const float*)d_in[6];
    const float* gru1_bih = (const float*)d_in[7];
    const float* gru1_bhh = (const float*)d_in[8];
    const float* gru2_wih = (const float*)d_in[9];
    const float* gru2_whh = (const float*)d_in[10];
    const float* gru2_bih = (const float*)d_in[11];
    const float* gru2_bhh = (const float*)d_in[12];
    const float* convQ_w = (const float*)d_in[13];
    const float* convQ_b = (const float*)d_in[14];
    const float* Wa_w = (const float*)d_in[15];
    const float* Wa_b = (const float*)d_in[16];
    const float* Ua_w = (const float*)d_in[17];
    const float* Ua_b = (const float*)d_in[18];
    const float* Uf_w = (const float*)d_in[19];
    const float* Uf_b = (const float*)d_in[20];
    const float* Va_w = (const float*)d_in[21];
    const float* Va_b = (const float*)d_in[22];
    const float* Ws_w = (const float*)d_in[23];
    const float* Ws_b = (const float*)d_in[24];
    const float* Wc_w = (const float*)d_in[25];
    const float* Wc_b = (const float*)d_in[26];
    const float* Wo_w = (const float*)d_in[27];
    const float* Wo_b = (const float*)d_in[28];

    float* out = (float*)d_out;
    float* out_logits = out;                         // 64*128
    float* out_h2 = out + BSZ * VOC;                 // 64*256
    float* out_alpha = out + BSZ * VOC + BSZ * HID;  // 64*1024

    float* ws = (float*)d_ws;
    float* ws_emb = ws;                          // 16384 floats
    float* ws_pred = ws + 16384;                 // 16384
    float* ws_q0 = ws + 32768;                   // 32768
    float* ws_et = ws + 65536;                   // 65536
    float* ws_ctx = ws + 131072;                 // 43776 (pad to 44032)
    float* ws_covb = ws + 175104;                // 512
    unsigned short* Ua_bf = (unsigned short*)(ws + 175616);  // 512*704*2B = 180224 floats
    unsigned short* W2_bf = (unsigned short*)(ws + 355840);  // 512*128*2B = 32768 floats
    // total 388608 floats = 1.55 MB

    k_prep_ua<<<NPP, 256, 0, stream>>>(Ua_w, Ua_bf);
    k_fold_w2<<<TAPP + 1, 256, 0, stream>>>(Uf_w, Uf_b, convQ_w, convQ_b, W2_bf, ws_covb);
    k_embed_gru1<<<BSZ, 256, 0, stream>>>(x, hidden, emb, gru1_wih, gru1_whh,
                                          gru1_bih, gru1_bhh, Wa_w, Wa_b,
                                          ws_covb, Ua_b,
                                          ws_emb, ws_pred, ws_q0);
    k_score<<<dim3(16, BSZ), 256, 0, stream>>>(feature, alpha, Ua_bf, W2_bf,
                                               ws_q0, Va_w, Va_b, ws_et);
    k_softmax<<<BSZ, 256, 0, stream>>>(ws_et, out_alpha);
    k_context<<<dim3(BSZ, 171), 256, 0, stream>>>(feature, out_alpha, ws_ctx);
    k_final<<<BSZ, 256, 0, stream>>>(ws_ctx, ws_pred, ws_emb, gru2_wih, gru2_whh,
                                     gru2_bih, gru2_bhh, Ws_w, Ws_b, Wc_w, Wc_b,
                                     Wo_w, Wo_b, out_logits, out_h2);
}